// Round 5
// baseline (212.119 us; speedup 1.0000x reference)
//
#include <hip/hip_runtime.h>
#include <hip/hip_cooperative_groups.h>
#include <math.h>

namespace cg = cooperative_groups;

typedef short bf16x8 __attribute__((ext_vector_type(8)));
typedef float f32x16 __attribute__((ext_vector_type(16)));

__device__ __forceinline__ unsigned short f2bf(float f) {
    union { float f; unsigned u; } x; x.f = f;
    unsigned r = x.u + 0x7FFFu + ((x.u >> 16) & 1u);
    return (unsigned short)(r >> 16);
}

// 8 consecutive k of row `row`; bias folded at k==Kreal; 0 beyond.
__device__ __forceinline__ bf16x8 conv8(const float* __restrict__ W,
                                        const float* __restrict__ bias,
                                        int row, int Kreal, int k0) {
    bf16x8 r;
    #pragma unroll
    for (int j = 0; j < 8; ++j) {
        int k = k0 + j;
        float v = (k < Kreal) ? W[(size_t)row * Kreal + k]
                              : ((k == Kreal) ? bias[row] : 0.f);
        r[j] = (short)f2bf(v);
    }
    return r;
}

// ---------------- Phase A: coef + x->frag-major bf16 + H tails + W->frag-major ----
__device__ void phaseA(
    const float* __restrict__ x,
    const float* __restrict__ W0, const float* __restrict__ W1, const float* __restrict__ W2,
    const float* __restrict__ bias0, const float* __restrict__ bias1, const float* __restrict__ bias2,
    float* __restrict__ coef, unsigned short* __restrict__ xf,
    unsigned short* __restrict__ H1f, unsigned short* __restrict__ H2f,
    unsigned short* __restrict__ Wf0, unsigned short* __restrict__ Wf1, unsigned short* __restrict__ Wf2,
    int bid, int tid, unsigned gsz)
{
    unsigned gtid = (unsigned)bid * 256u + (unsigned)tid;

    // coef per sample
    for (unsigned b = gtid; b < 1024u; b += gsz) {
        float phase = x[b * 343u + 342u];
        float ps = 4.0f * phase;
        int k1 = (int)ps;
        float mu = ps - (float)k1;
        k1 &= 3;
        float mu2 = mu * mu, mu3 = mu2 * mu;
        float c0 = -0.5f * mu3 +        mu2 - 0.5f * mu;
        float c1 =  1.5f * mu3 - 2.5f * mu2 + 1.0f;
        float c2 = -1.5f * mu3 + 2.0f * mu2 + 0.5f * mu;
        float c3 =  0.5f * mu3 - 0.5f * mu2;
        float cc[4];
        cc[(k1 + 3) & 3] = c0;
        cc[k1]           = c1;
        cc[(k1 + 1) & 3] = c2;
        cc[(k1 + 2) & 3] = c3;
        *(float4*)(coef + b * 4) = make_float4(cc[0], cc[1], cc[2], cc[3]);
    }

    // x -> xf frag-major (32 bt x 24 ks x 64 lanes x 8), bias col at k==342
    for (unsigned c = gtid; c < 32u * 24u * 64u; c += gsz) {
        unsigned lane = c & 63u, r = c >> 6;
        unsigned ks = r % 24u, bt = r / 24u;
        int b  = (int)(bt * 32u + (lane & 31u));
        int k0 = (int)(ks * 16u + (lane >> 5) * 8u);
        bf16x8 v;
        #pragma unroll
        for (int j = 0; j < 8; ++j) {
            int k = k0 + j;
            unsigned short s;
            if (k < 342)       s = f2bf(x[(size_t)b * 343 + k]);
            else if (k == 342) s = 0x3F80;
            else               s = 0;
            v[j] = (short)s;
        }
        *(bf16x8*)(xf + (size_t)c * 8) = v;
    }

    // H1f/H2f constant tails: ks in [32,36): k==512 -> 1.0, else 0
    for (unsigned c = gtid; c < 32u * 4u * 64u; c += gsz) {
        unsigned lane = c & 63u, r = c >> 6;
        unsigned kk = r & 3u, bt = r >> 2;
        size_t off = ((size_t)(bt * 36u + 32u + kk) * 64u + lane) * 8u;
        bf16x8 v;
        #pragma unroll
        for (int j = 0; j < 8; ++j)
            v[j] = (short)((kk == 0u && (lane >> 5) == 0u && j == 0) ? 0x3F80 : 0);
        *(bf16x8*)(H1f + off) = v;
        *(bf16x8*)(H2f + off) = v;
    }

    // W -> frag-major, destination-owned (coalesced 16B writes)
    constexpr unsigned C0 = 4u * 16 * 24 * 64;   // 98304
    constexpr unsigned C1 = 4u * 16 * 36 * 64;   // 147456
    constexpr unsigned C2 = 4u * 10 * 36 * 64;   // 92160
    for (unsigned c = gtid; c < C0 + C1 + C2; c += gsz) {
        bf16x8 v;
        unsigned short* dst;
        if (c < C0) {
            unsigned lane = c & 63u, r = c >> 6, ks = r % 24u, t = r / 24u;
            int o  = (int)((t & 15u) * 32u + (lane & 31u));
            int k0 = (int)(ks * 16u + (lane >> 5) * 8u);
            v = conv8(W0, bias0, (int)(t >> 4) * 512 + o, 342, k0);
            dst = Wf0 + (size_t)c * 8;
        } else if (c < C0 + C1) {
            unsigned cc = c - C0;
            unsigned lane = cc & 63u, r = cc >> 6, ks = r % 36u, t = r / 36u;
            int o  = (int)((t & 15u) * 32u + (lane & 31u));
            int k0 = (int)(ks * 16u + (lane >> 5) * 8u);
            v = conv8(W1, bias1, (int)(t >> 4) * 512 + o, 512, k0);
            dst = Wf1 + (size_t)cc * 8;
        } else {
            unsigned cc = c - C0 - C1;
            unsigned lane = cc & 63u, r = cc >> 6, ks = r % 36u, t = r / 36u;
            unsigned ot = t % 10u, n = t / 10u;
            int o  = (int)(ot * 32u + (lane & 31u));
            int k0 = (int)(ks * 16u + (lane >> 5) * 8u);
            if (o < 311) {
                v = conv8(W2, bias2, (int)n * 311 + o, 512, k0);
            } else {
                #pragma unroll
                for (int j = 0; j < 8; ++j) v[j] = 0;
            }
            dst = Wf2 + (size_t)cc * 8;
        }
        *(bf16x8*)dst = v;
    }
}

// ---------------- Layer: tile 32o x 32b x 4 banks; 4-wave split-K ----------------
// A and B frags both frag-major in global (coalesced dwordx4, L2-resident).
// Split-K reduce via 12KB LDS; wave 0 does coef-combine + ELU + store.
// bf16 outputs are written directly in next layer's B-frag-major layout (NKS_next=36).
template<bool ELU, bool OUT_BF16, int KP, int OPAD>
__device__ __forceinline__ void layer_phase(
    const unsigned short* __restrict__ Wf,   // (4, OPAD/32, KP/16, 64, 8)
    const unsigned short* __restrict__ Hf,   // (32, KP/16, 64, 8)
    const float* __restrict__ coef,          // (1024, 4)
    unsigned short* __restrict__ HoutF,      // frag-major (32, 36, 64, 8)  [OUT_BF16]
    float* __restrict__ outF, int Oreal,     // (1024, Oreal) row-major     [!OUT_BF16]
    float* red, int bid, int tid, int gdim)
{
    constexpr int NOT = OPAD / 32, NKS = KP / 16, KSQ = NKS / 4;
    const int lane = tid & 63, w = tid >> 6;
    const int m = lane & 31, h = lane >> 5;
    const size_t nstr = (size_t)NOT * NKS * 512;

    for (int t = bid; t < NOT * 32; t += gdim) {
        const int ot = t >> 5, bt = t & 31;
        const unsigned short* wbase = Wf + ((size_t)ot * NKS + w * KSQ) * 512 + (size_t)lane * 8;
        const unsigned short* bbase = Hf + ((size_t)bt * NKS + w * KSQ) * 512 + (size_t)lane * 8;

        f32x16 acc0 = {}, acc1 = {}, acc2 = {}, acc3 = {};
        #pragma unroll
        for (int s = 0; s < KSQ; ++s) {
            bf16x8 bfr = *(const bf16x8*)(bbase + (size_t)s * 512);
            bf16x8 a0 = *(const bf16x8*)(wbase + (size_t)s * 512);
            bf16x8 a1 = *(const bf16x8*)(wbase + nstr + (size_t)s * 512);
            bf16x8 a2 = *(const bf16x8*)(wbase + 2 * nstr + (size_t)s * 512);
            bf16x8 a3 = *(const bf16x8*)(wbase + 3 * nstr + (size_t)s * 512);
            acc0 = __builtin_amdgcn_mfma_f32_32x32x16_bf16(a0, bfr, acc0, 0, 0, 0);
            acc1 = __builtin_amdgcn_mfma_f32_32x32x16_bf16(a1, bfr, acc1, 0, 0, 0);
            acc2 = __builtin_amdgcn_mfma_f32_32x32x16_bf16(a2, bfr, acc2, 0, 0, 0);
            acc3 = __builtin_amdgcn_mfma_f32_32x32x16_bf16(a3, bfr, acc3, 0, 0, 0);
        }

        const int b = bt * 32 + m;
        float4 cf = *(const float4*)(coef + b * 4);
        float sv[16];
        #pragma unroll
        for (int r = 0; r < 16; ++r)
            sv[r] = cf.x * acc0[r] + cf.y * acc1[r] + cf.z * acc2[r] + cf.w * acc3[r];

        __syncthreads();   // red safe to reuse (also separates t-iterations)
        if (w > 0) {
            #pragma unroll
            for (int g = 0; g < 4; ++g)
                #pragma unroll
                for (int j = 0; j < 4; ++j) {
                    int row = 8 * g + 4 * h + j;
                    red[(w - 1) * 1024 + row * 32 + m] = sv[g * 4 + j];
                }
        }
        __syncthreads();
        if (w == 0) {
            #pragma unroll
            for (int g = 0; g < 4; ++g) {
                float vv[4];
                #pragma unroll
                for (int j = 0; j < 4; ++j) {
                    int row = 8 * g + 4 * h + j;
                    float v = sv[g * 4 + j] + red[row * 32 + m]
                            + red[1024 + row * 32 + m] + red[2048 + row * 32 + m];
                    if (ELU) v = (v > 0.f) ? v : expm1f(v);
                    vv[j] = v;
                }
                if (OUT_BF16) {
                    // o = ot*32 + 8g + 4h + j  ->  B-frag pos, NKS_next = 36
                    size_t off = (((size_t)bt * 36 + ot * 2 + (g >> 1)) * 64
                                  + (g & 1) * 32 + m) * 8 + 4 * h;
                    ushort4 pk;
                    pk.x = f2bf(vv[0]); pk.y = f2bf(vv[1]); pk.z = f2bf(vv[2]); pk.w = f2bf(vv[3]);
                    *(ushort4*)(HoutF + off) = pk;
                } else {
                    int orow = ot * 32 + 8 * g + 4 * h;
                    #pragma unroll
                    for (int j = 0; j < 4; ++j)
                        if (orow + j < Oreal) outF[(size_t)b * Oreal + orow + j] = vv[j];
                }
            }
        }
    }
}

#define PFNN_ARGS \
    const float* __restrict__ x, \
    const float* __restrict__ W0, const float* __restrict__ W1, const float* __restrict__ W2, \
    const float* __restrict__ bias0, const float* __restrict__ bias1, const float* __restrict__ bias2, \
    float* __restrict__ outF, float* __restrict__ coef, \
    unsigned short* __restrict__ xf, \
    unsigned short* __restrict__ H1f, unsigned short* __restrict__ H2f, \
    unsigned short* __restrict__ Wf0, unsigned short* __restrict__ Wf1, unsigned short* __restrict__ Wf2

__global__ void __launch_bounds__(256, 2) pfnn_fused(PFNN_ARGS) {
    __shared__ float red[3 * 1024];
    const int bid = blockIdx.x, tid = threadIdx.x, gdim = gridDim.x;
    cg::grid_group grid = cg::this_grid();

    phaseA(x, W0, W1, W2, bias0, bias1, bias2, coef, xf, H1f, H2f, Wf0, Wf1, Wf2,
           bid, tid, (unsigned)gdim * 256u);
    grid.sync();
    layer_phase<true,  true,  384, 512>(Wf0, xf,  coef, H1f, nullptr, 512, red, bid, tid, gdim);
    grid.sync();
    layer_phase<true,  true,  576, 512>(Wf1, H1f, coef, H2f, nullptr, 512, red, bid, tid, gdim);
    grid.sync();
    layer_phase<false, false, 576, 320>(Wf2, H2f, coef, nullptr, outF, 311, red, bid, tid, gdim);
}

// -------- fallback (plain dispatches of the same phases) --------
__global__ void __launch_bounds__(256) phaseA_kernel(PFNN_ARGS) {
    phaseA(x, W0, W1, W2, bias0, bias1, bias2, coef, xf, H1f, H2f, Wf0, Wf1, Wf2,
           blockIdx.x, threadIdx.x, gridDim.x * 256u);
    (void)outF;
}
__global__ void __launch_bounds__(256, 2) layer0_kernel(PFNN_ARGS) {
    __shared__ float red[3 * 1024];
    layer_phase<true,  true,  384, 512>(Wf0, xf,  coef, H1f, nullptr, 512, red, blockIdx.x, threadIdx.x, gridDim.x);
    (void)outF;
}
__global__ void __launch_bounds__(256, 2) layer1_kernel(PFNN_ARGS) {
    __shared__ float red[3 * 1024];
    layer_phase<true,  true,  576, 512>(Wf1, H1f, coef, H2f, nullptr, 512, red, blockIdx.x, threadIdx.x, gridDim.x);
    (void)outF;
}
__global__ void __launch_bounds__(256, 2) layer2_kernel(PFNN_ARGS) {
    __shared__ float red[3 * 1024];
    layer_phase<false, false, 576, 320>(Wf2, H2f, coef, nullptr, outF, 311, red, blockIdx.x, threadIdx.x, gridDim.x);
}

extern "C" void kernel_launch(void* const* d_in, const int* in_sizes, int n_in,
                              void* d_out, int out_size, void* d_ws, size_t ws_size,
                              hipStream_t stream) {
    (void)in_sizes; (void)n_in; (void)out_size; (void)ws_size;
    const float* x  = (const float*)d_in[0];
    const float* W0 = (const float*)d_in[1];
    const float* W1 = (const float*)d_in[2];
    const float* W2 = (const float*)d_in[3];
    const float* b0 = (const float*)d_in[4];
    const float* b1 = (const float*)d_in[5];
    const float* b2 = (const float*)d_in[6];
    float* out = (float*)d_out;

    char* wsb = (char*)d_ws;
    float*          coef = (float*)(wsb + 0);                  //   16384 B
    unsigned short* xf   = (unsigned short*)(wsb + 16384);     //  786432 el (32,24,64,8)
    unsigned short* H1f  = (unsigned short*)(wsb + 802816);    // 1179648 el (32,36,64,8)
    unsigned short* H2f  = (unsigned short*)(wsb + 1982464);
    unsigned short* Wf0  = (unsigned short*)(wsb + 3162112);   // (4,16,24,64,8)
    unsigned short* Wf1  = (unsigned short*)(wsb + 4734976);   // (4,16,36,64,8)
    unsigned short* Wf2  = (unsigned short*)(wsb + 7094272);   // (4,10,36,64,8)

    int maxb = 0;
    hipError_t qe = hipOccupancyMaxActiveBlocksPerMultiprocessor(
        &maxb, (const void*)pfnn_fused, 256, 0);
    int grid = 256;                                   // 1 block/CU always co-resident
    if (qe == hipSuccess && maxb >= 2) grid = 512;    // 2 blocks/CU confirmed

    void* args[] = {
        (void*)&x, (void*)&W0, (void*)&W1, (void*)&W2,
        (void*)&b0, (void*)&b1, (void*)&b2, (void*)&out,
        (void*)&coef, (void*)&xf, (void*)&H1f, (void*)&H2f,
        (void*)&Wf0, (void*)&Wf1, (void*)&Wf2
    };
    hipError_t e = hipLaunchCooperativeKernel((const void*)pfnn_fused,
                                              dim3(grid), dim3(256), args, 0, stream);
    if (e != hipSuccess) {
        (void)hipGetLastError();  // clear error state, take plain-dispatch path
        phaseA_kernel<<<dim3(512), dim3(256), 0, stream>>>(x, W0, W1, W2, b0, b1, b2, out, coef, xf, H1f, H2f, Wf0, Wf1, Wf2);
        layer0_kernel<<<dim3(512), dim3(256), 0, stream>>>(x, W0, W1, W2, b0, b1, b2, out, coef, xf, H1f, H2f, Wf0, Wf1, Wf2);
        layer1_kernel<<<dim3(512), dim3(256), 0, stream>>>(x, W0, W1, W2, b0, b1, b2, out, coef, xf, H1f, H2f, Wf0, Wf1, Wf2);
        layer2_kernel<<<dim3(320), dim3(256), 0, stream>>>(x, W0, W1, W2, b0, b1, b2, out, coef, xf, H1f, H2f, Wf0, Wf1, Wf2);
    }
}

// Round 6
// 100.697 us; speedup vs baseline: 2.1065x; 2.1065x over previous
//
#include <hip/hip_runtime.h>
#include <math.h>

typedef short bf16x8 __attribute__((ext_vector_type(8)));
typedef float f32x16 __attribute__((ext_vector_type(16)));

__device__ __forceinline__ unsigned short f2bf(float f) {
    union { float f; unsigned u; } x; x.f = f;
    unsigned r = x.u + 0x7FFFu + ((x.u >> 16) & 1u);
    return (unsigned short)(r >> 16);
}

// 8 consecutive k of row `row`; bias folded at k==Kreal; 0 beyond.
__device__ __forceinline__ bf16x8 conv8(const float* __restrict__ W,
                                        const float* __restrict__ bias,
                                        int row, int Kreal, int k0) {
    bf16x8 r;
    #pragma unroll
    for (int j = 0; j < 8; ++j) {
        int k = k0 + j;
        float v = (k < Kreal) ? W[(size_t)row * Kreal + k]
                              : ((k == Kreal) ? bias[row] : 0.f);
        r[j] = (short)f2bf(v);
    }
    return r;
}

// ---------------- Phase A: coef + x->frag-major + H tails + W->frag-major --------
// (HW-verified in round 5.)
__global__ void __launch_bounds__(256) phaseA_kernel(
    const float* __restrict__ x,
    const float* __restrict__ W0, const float* __restrict__ W1, const float* __restrict__ W2,
    const float* __restrict__ bias0, const float* __restrict__ bias1, const float* __restrict__ bias2,
    float* __restrict__ coef, unsigned short* __restrict__ xf,
    unsigned short* __restrict__ H1f, unsigned short* __restrict__ H2f,
    unsigned short* __restrict__ Wf0, unsigned short* __restrict__ Wf1, unsigned short* __restrict__ Wf2)
{
    const unsigned gtid = blockIdx.x * 256u + threadIdx.x;
    const unsigned gsz  = gridDim.x * 256u;

    // coef per sample
    for (unsigned b = gtid; b < 1024u; b += gsz) {
        float phase = x[b * 343u + 342u];
        float ps = 4.0f * phase;
        int k1 = (int)ps;
        float mu = ps - (float)k1;
        k1 &= 3;
        float mu2 = mu * mu, mu3 = mu2 * mu;
        float c0 = -0.5f * mu3 +        mu2 - 0.5f * mu;
        float c1 =  1.5f * mu3 - 2.5f * mu2 + 1.0f;
        float c2 = -1.5f * mu3 + 2.0f * mu2 + 0.5f * mu;
        float c3 =  0.5f * mu3 - 0.5f * mu2;
        float cc[4];
        cc[(k1 + 3) & 3] = c0;
        cc[k1]           = c1;
        cc[(k1 + 1) & 3] = c2;
        cc[(k1 + 2) & 3] = c3;
        *(float4*)(coef + b * 4) = make_float4(cc[0], cc[1], cc[2], cc[3]);
    }

    // x -> xf frag-major (32 bt x 24 ks x 64 lanes x 8), bias col at k==342
    for (unsigned c = gtid; c < 32u * 24u * 64u; c += gsz) {
        unsigned lane = c & 63u, r = c >> 6;
        unsigned ks = r % 24u, bt = r / 24u;
        int b  = (int)(bt * 32u + (lane & 31u));
        int k0 = (int)(ks * 16u + (lane >> 5) * 8u);
        bf16x8 v;
        #pragma unroll
        for (int j = 0; j < 8; ++j) {
            int k = k0 + j;
            unsigned short s;
            if (k < 342)       s = f2bf(x[(size_t)b * 343 + k]);
            else if (k == 342) s = 0x3F80;
            else               s = 0;
            v[j] = (short)s;
        }
        *(bf16x8*)(xf + (size_t)c * 8) = v;
    }

    // H1f/H2f constant tails: ks in [32,36): k==512 -> 1.0, else 0
    for (unsigned c = gtid; c < 32u * 4u * 64u; c += gsz) {
        unsigned lane = c & 63u, r = c >> 6;
        unsigned kk = r & 3u, bt = r >> 2;
        size_t off = ((size_t)(bt * 36u + 32u + kk) * 64u + lane) * 8u;
        bf16x8 v;
        #pragma unroll
        for (int j = 0; j < 8; ++j)
            v[j] = (short)((kk == 0u && (lane >> 5) == 0u && j == 0) ? 0x3F80 : 0);
        *(bf16x8*)(H1f + off) = v;
        *(bf16x8*)(H2f + off) = v;
    }

    // W -> frag-major, destination-owned (coalesced 16B writes)
    constexpr unsigned C0 = 4u * 16 * 24 * 64;   // 98304
    constexpr unsigned C1 = 4u * 16 * 36 * 64;   // 147456
    constexpr unsigned C2 = 4u * 10 * 36 * 64;   // 92160
    for (unsigned c = gtid; c < C0 + C1 + C2; c += gsz) {
        bf16x8 v;
        unsigned short* dst;
        if (c < C0) {
            unsigned lane = c & 63u, r = c >> 6, ks = r % 24u, t = r / 24u;
            int o  = (int)((t & 15u) * 32u + (lane & 31u));
            int k0 = (int)(ks * 16u + (lane >> 5) * 8u);
            v = conv8(W0, bias0, (int)(t >> 4) * 512 + o, 342, k0);
            dst = Wf0 + (size_t)c * 8;
        } else if (c < C0 + C1) {
            unsigned cc = c - C0;
            unsigned lane = cc & 63u, r = cc >> 6, ks = r % 36u, t = r / 36u;
            int o  = (int)((t & 15u) * 32u + (lane & 31u));
            int k0 = (int)(ks * 16u + (lane >> 5) * 8u);
            v = conv8(W1, bias1, (int)(t >> 4) * 512 + o, 512, k0);
            dst = Wf1 + (size_t)cc * 8;
        } else {
            unsigned cc = c - C0 - C1;
            unsigned lane = cc & 63u, r = cc >> 6, ks = r % 36u, t = r / 36u;
            unsigned ot = t % 10u, n = t / 10u;
            int o  = (int)(ot * 32u + (lane & 31u));
            int k0 = (int)(ks * 16u + (lane >> 5) * 8u);
            if (o < 311) {
                v = conv8(W2, bias2, (int)n * 311 + o, 512, k0);
            } else {
                #pragma unroll
                for (int j = 0; j < 8; ++j) v[j] = 0;
            }
            dst = Wf2 + (size_t)cc * 8;
        }
        *(bf16x8*)dst = v;
    }
}

// ---------------- Layer: tile 32o x 32b x 4 banks; 4-wave split-K ----------------
// A and B frags both frag-major in global (coalesced dwordx4, L2-resident).
// Split-K reduce via 12KB LDS; wave 0 does coef-combine + ELU + store.
// bf16 outputs written directly in next layer's B-frag-major layout (NKS_next=36).
// (HW-verified in round 5.)
template<bool ELU, bool OUT_BF16, int KP, int OPAD>
__device__ __forceinline__ void layer_phase(
    const unsigned short* __restrict__ Wf,   // (4, OPAD/32, KP/16, 64, 8)
    const unsigned short* __restrict__ Hf,   // (32, KP/16, 64, 8)
    const float* __restrict__ coef,          // (1024, 4)
    unsigned short* __restrict__ HoutF,      // frag-major (32, 36, 64, 8)  [OUT_BF16]
    float* __restrict__ outF, int Oreal,     // (1024, Oreal) row-major     [!OUT_BF16]
    float* red, int bid, int tid, int gdim)
{
    constexpr int NOT = OPAD / 32, NKS = KP / 16, KSQ = NKS / 4;
    const int lane = tid & 63, w = tid >> 6;
    const int m = lane & 31, h = lane >> 5;
    const size_t nstr = (size_t)NOT * NKS * 512;

    for (int t = bid; t < NOT * 32; t += gdim) {
        const int ot = t >> 5, bt = t & 31;
        const unsigned short* wbase = Wf + ((size_t)ot * NKS + w * KSQ) * 512 + (size_t)lane * 8;
        const unsigned short* bbase = Hf + ((size_t)bt * NKS + w * KSQ) * 512 + (size_t)lane * 8;

        f32x16 acc0 = {}, acc1 = {}, acc2 = {}, acc3 = {};
        #pragma unroll
        for (int s = 0; s < KSQ; ++s) {
            bf16x8 bfr = *(const bf16x8*)(bbase + (size_t)s * 512);
            bf16x8 a0 = *(const bf16x8*)(wbase + (size_t)s * 512);
            bf16x8 a1 = *(const bf16x8*)(wbase + nstr + (size_t)s * 512);
            bf16x8 a2 = *(const bf16x8*)(wbase + 2 * nstr + (size_t)s * 512);
            bf16x8 a3 = *(const bf16x8*)(wbase + 3 * nstr + (size_t)s * 512);
            acc0 = __builtin_amdgcn_mfma_f32_32x32x16_bf16(a0, bfr, acc0, 0, 0, 0);
            acc1 = __builtin_amdgcn_mfma_f32_32x32x16_bf16(a1, bfr, acc1, 0, 0, 0);
            acc2 = __builtin_amdgcn_mfma_f32_32x32x16_bf16(a2, bfr, acc2, 0, 0, 0);
            acc3 = __builtin_amdgcn_mfma_f32_32x32x16_bf16(a3, bfr, acc3, 0, 0, 0);
        }

        const int b = bt * 32 + m;
        float4 cf = *(const float4*)(coef + b * 4);
        float sv[16];
        #pragma unroll
        for (int r = 0; r < 16; ++r)
            sv[r] = cf.x * acc0[r] + cf.y * acc1[r] + cf.z * acc2[r] + cf.w * acc3[r];

        __syncthreads();   // red safe to reuse (also separates t-iterations)
        if (w > 0) {
            #pragma unroll
            for (int g = 0; g < 4; ++g)
                #pragma unroll
                for (int j = 0; j < 4; ++j) {
                    int row = 8 * g + 4 * h + j;
                    red[(w - 1) * 1024 + row * 32 + m] = sv[g * 4 + j];
                }
        }
        __syncthreads();
        if (w == 0) {
            #pragma unroll
            for (int g = 0; g < 4; ++g) {
                float vv[4];
                #pragma unroll
                for (int j = 0; j < 4; ++j) {
                    int row = 8 * g + 4 * h + j;
                    float v = sv[g * 4 + j] + red[row * 32 + m]
                            + red[1024 + row * 32 + m] + red[2048 + row * 32 + m];
                    if (ELU) v = (v > 0.f) ? v : expm1f(v);
                    vv[j] = v;
                }
                if (OUT_BF16) {
                    // o = ot*32 + 8g + 4h + j  ->  B-frag pos, NKS_next = 36
                    size_t off = (((size_t)bt * 36 + ot * 2 + (g >> 1)) * 64
                                  + (g & 1) * 32 + m) * 8 + 4 * h;
                    ushort4 pk;
                    pk.x = f2bf(vv[0]); pk.y = f2bf(vv[1]); pk.z = f2bf(vv[2]); pk.w = f2bf(vv[3]);
                    *(ushort4*)(HoutF + off) = pk;
                } else {
                    int orow = ot * 32 + 8 * g + 4 * h;
                    #pragma unroll
                    for (int j = 0; j < 4; ++j)
                        if (orow + j < Oreal) outF[(size_t)b * Oreal + orow + j] = vv[j];
                }
            }
        }
    }
}

__global__ void __launch_bounds__(256, 2) layer0_kernel(
    const unsigned short* __restrict__ Wf0, const unsigned short* __restrict__ xf,
    const float* __restrict__ coef, unsigned short* __restrict__ H1f)
{
    __shared__ float red[3 * 1024];
    layer_phase<true, true, 384, 512>(Wf0, xf, coef, H1f, nullptr, 512,
                                      red, blockIdx.x, threadIdx.x, gridDim.x);
}
__global__ void __launch_bounds__(256, 2) layer1_kernel(
    const unsigned short* __restrict__ Wf1, const unsigned short* __restrict__ H1f,
    const float* __restrict__ coef, unsigned short* __restrict__ H2f)
{
    __shared__ float red[3 * 1024];
    layer_phase<true, true, 576, 512>(Wf1, H1f, coef, H2f, nullptr, 512,
                                      red, blockIdx.x, threadIdx.x, gridDim.x);
}
__global__ void __launch_bounds__(256, 2) layer2_kernel(
    const unsigned short* __restrict__ Wf2, const unsigned short* __restrict__ H2f,
    const float* __restrict__ coef, float* __restrict__ outF)
{
    __shared__ float red[3 * 1024];
    layer_phase<false, false, 576, 320>(Wf2, H2f, coef, nullptr, outF, 311,
                                        red, blockIdx.x, threadIdx.x, gridDim.x);
}

extern "C" void kernel_launch(void* const* d_in, const int* in_sizes, int n_in,
                              void* d_out, int out_size, void* d_ws, size_t ws_size,
                              hipStream_t stream) {
    (void)in_sizes; (void)n_in; (void)out_size; (void)ws_size;
    const float* x  = (const float*)d_in[0];
    const float* W0 = (const float*)d_in[1];
    const float* W1 = (const float*)d_in[2];
    const float* W2 = (const float*)d_in[3];
    const float* b0 = (const float*)d_in[4];
    const float* b1 = (const float*)d_in[5];
    const float* b2 = (const float*)d_in[6];
    float* out = (float*)d_out;

    char* wsb = (char*)d_ws;
    float*          coef = (float*)(wsb + 0);                  //   16384 B
    unsigned short* xf   = (unsigned short*)(wsb + 16384);     //  786432 el (32,24,64,8)
    unsigned short* H1f  = (unsigned short*)(wsb + 802816);    // (32,36,64,8)
    unsigned short* H2f  = (unsigned short*)(wsb + 1982464);   // (32,36,64,8)
    unsigned short* Wf0  = (unsigned short*)(wsb + 3162112);   // (4,16,24,64,8)
    unsigned short* Wf1  = (unsigned short*)(wsb + 4734976);   // (4,16,36,64,8)
    unsigned short* Wf2  = (unsigned short*)(wsb + 7094272);   // (4,10,36,64,8)

    phaseA_kernel<<<dim3(512), dim3(256), 0, stream>>>(
        x, W0, W1, W2, b0, b1, b2, coef, xf, H1f, H2f, Wf0, Wf1, Wf2);
    layer0_kernel<<<dim3(512), dim3(256), 0, stream>>>(Wf0, xf,  coef, H1f);
    layer1_kernel<<<dim3(512), dim3(256), 0, stream>>>(Wf1, H1f, coef, H2f);
    layer2_kernel<<<dim3(320), dim3(256), 0, stream>>>(Wf2, H2f, coef, out);
}

// Round 7
// 94.909 us; speedup vs baseline: 2.2350x; 1.0610x over previous
//
#include <hip/hip_runtime.h>
#include <math.h>

typedef short bf16x8 __attribute__((ext_vector_type(8)));
typedef float f32x16 __attribute__((ext_vector_type(16)));

__device__ __forceinline__ unsigned short f2bf(float f) {
    union { float f; unsigned u; } x; x.f = f;
    unsigned r = x.u + 0x7FFFu + ((x.u >> 16) & 1u);
    return (unsigned short)(r >> 16);
}

// ---- Transpose one 32-row tile of fp32 (row-major, ld=ldsrc) into frag-major bf16.
// Bias folded at k==Kreal (bias==nullptr -> 1.0). Rows >= rowlimit are zero.
// dst tile layout: (ks, 64 lanes, 8) with o = lane&31, k = ks*16 + (lane>>5)*8 + j.
template<int NKS_T>
__device__ void transpose_tile(const float* __restrict__ W, const float* __restrict__ bias,
                               int rowbase, int rowlimit, int Kreal, int ldsrc,
                               unsigned short* __restrict__ dst, float* s, int tid)
{
    constexpr int NCHK = NKS_T / 4;          // 64-k chunks
    const int r = tid >> 3, l = tid & 7;     // staging: row r, 8 lanes/row
    const int ks_l = tid >> 6, lane = tid & 63;
    const int m = lane & 31, h = lane >> 5;
    for (int kc = 0; kc < NCHK; ++kc) {
        {   // stage 32 rows x 64 k into LDS (stride 66: conflict-free-ish)
            int kb = kc * 64 + l * 8;
            const bool rv = r < rowlimit;
            const float* src = W + (size_t)(rowbase + r) * ldsrc + kb;
            float v[8];
            if (rv && kb + 7 < Kreal) {
                #pragma unroll
                for (int i = 0; i < 8; ++i) v[i] = src[i];
            } else {
                #pragma unroll
                for (int i = 0; i < 8; ++i) {
                    int k = kb + i;
                    v[i] = (rv && k < Kreal) ? src[i]
                         : ((rv && k == Kreal) ? (bias ? bias[rowbase + r] : 1.0f) : 0.f);
                }
            }
            #pragma unroll
            for (int i = 0; i < 8; ++i) s[r * 66 + l * 8 + i] = v[i];
        }
        __syncthreads();
        {   // frag gather + bf16 convert + coalesced 16B store; wave ks_l owns ks
            bf16x8 pk;
            #pragma unroll
            for (int j = 0; j < 8; ++j)
                pk[j] = (short)f2bf(s[m * 66 + ks_l * 16 + h * 8 + j]);
            *(bf16x8*)(dst + ((size_t)(kc * 4 + ks_l) * 64 + lane) * 8) = pk;
        }
        __syncthreads();
    }
}

// ---------------- Phase A: coef + xf + tails + W->frag-major (all transposed) -----
// blocks 0..31: xf tile bt=bid (+coef +H tails); 32..95: W0; 96..159: W1; 160..199: W2.
__global__ void __launch_bounds__(256) phaseA_kernel(
    const float* __restrict__ x,
    const float* __restrict__ W0, const float* __restrict__ W1, const float* __restrict__ W2,
    const float* __restrict__ bias0, const float* __restrict__ bias1, const float* __restrict__ bias2,
    float* __restrict__ coef, unsigned short* __restrict__ xf,
    unsigned short* __restrict__ H1f, unsigned short* __restrict__ H2f,
    unsigned short* __restrict__ Wf0, unsigned short* __restrict__ Wf1, unsigned short* __restrict__ Wf2)
{
    __shared__ float s[32 * 66];
    const int bid = blockIdx.x, tid = threadIdx.x;

    if (bid < 32) {
        const int bt = bid;
        // coef for this tile's 32 samples
        if (tid < 32) {
            int b = bt * 32 + tid;
            float phase = x[(size_t)b * 343 + 342];
            float ps = 4.0f * phase;
            int k1 = (int)ps;
            float mu = ps - (float)k1;
            k1 &= 3;
            float mu2 = mu * mu, mu3 = mu2 * mu;
            float c0 = -0.5f * mu3 +        mu2 - 0.5f * mu;
            float c1 =  1.5f * mu3 - 2.5f * mu2 + 1.0f;
            float c2 = -1.5f * mu3 + 2.0f * mu2 + 0.5f * mu;
            float c3 =  0.5f * mu3 - 0.5f * mu2;
            float cc[4];
            cc[(k1 + 3) & 3] = c0;
            cc[k1]           = c1;
            cc[(k1 + 1) & 3] = c2;
            cc[(k1 + 2) & 3] = c3;
            *(float4*)(coef + b * 4) = make_float4(cc[0], cc[1], cc[2], cc[3]);
        }
        // H1f/H2f constant tails for this bt: ks 32..35 (k==512 -> 1.0)
        {
            int kk = tid >> 6, lane = tid & 63;
            size_t off = ((size_t)(bt * 36 + 32 + kk) * 64 + lane) * 8;
            bf16x8 v;
            #pragma unroll
            for (int j = 0; j < 8; ++j)
                v[j] = (short)((kk == 0 && (lane >> 5) == 0 && j == 0) ? 0x3F80 : 0);
            *(bf16x8*)(H1f + off) = v;
            *(bf16x8*)(H2f + off) = v;
        }
        // x tile -> xf frag-major (Kreal=342, ld=343, bias col = 1.0)
        transpose_tile<24>(x, nullptr, bt * 32, 32, 342, 343,
                           xf + (size_t)bt * 24 * 512, s, tid);
    } else if (bid < 96) {
        int idx = bid - 32, n = idx >> 4, ot = idx & 15;
        transpose_tile<24>(W0, bias0, n * 512 + ot * 32, 32, 342, 342,
                           Wf0 + (size_t)(n * 16 + ot) * 24 * 512, s, tid);
    } else if (bid < 160) {
        int idx = bid - 96, n = idx >> 4, ot = idx & 15;
        transpose_tile<36>(W1, bias1, n * 512 + ot * 32, 32, 512, 512,
                           Wf1 + (size_t)(n * 16 + ot) * 36 * 512, s, tid);
    } else {
        int idx = bid - 160, n = idx / 10, ot = idx % 10;
        int rl = 311 - ot * 32; if (rl > 32) rl = 32;
        transpose_tile<36>(W2, bias2, n * 311 + ot * 32, rl, 512, 512,
                           Wf2 + (size_t)(n * 10 + ot) * 36 * 512, s, tid);
    }
}

// ---------------- Layer: tile 32o x 32b x 4 banks; 4-wave split-K -----------------
// Register double-buffered K-loop (chunks of 3 steps, ~15 loads in flight).
// Parallel epilogue: all waves dump partial planes to LDS; wave w reduces g=w rows.
// Layouts identical to round-5/6 HW-verified versions.
template<bool ELU, bool OUT_BF16, int KP, int OPAD>
__device__ __forceinline__ void layer_phase(
    const unsigned short* __restrict__ Wf,   // (4, OPAD/32, KP/16, 64, 8)
    const unsigned short* __restrict__ Hf,   // (32, KP/16, 64, 8)
    const float* __restrict__ coef,          // (1024, 4)
    unsigned short* __restrict__ HoutF,      // frag-major (32, 36, 64, 8)  [OUT_BF16]
    float* __restrict__ outF, int Oreal,     // (1024, Oreal) row-major     [!OUT_BF16]
    float* red, int bid, int tid)
{
    constexpr int NOT = OPAD / 32, NKS = KP / 16, KSQ = NKS / 4;
    constexpr int CH = 3, NC2 = KSQ / CH;    // 6->2, 9->3
    const int lane = tid & 63, w = tid >> 6;
    const int m = lane & 31, h = lane >> 5;
    const size_t nstr = (size_t)NOT * NKS * 512;

    const int ot = bid >> 5, bt = bid & 31;
    const unsigned short* wbase = Wf + ((size_t)ot * NKS + w * KSQ) * 512 + (size_t)lane * 8;
    const unsigned short* bbase = Hf + ((size_t)bt * NKS + w * KSQ) * 512 + (size_t)lane * 8;

    f32x16 acc0 = {}, acc1 = {}, acc2 = {}, acc3 = {};
    bf16x8 Ab[2][CH][4], Bb[2][CH];

    #pragma unroll
    for (int sI = 0; sI < CH; ++sI) {
        Bb[0][sI] = *(const bf16x8*)(bbase + (size_t)sI * 512);
        #pragma unroll
        for (int n = 0; n < 4; ++n)
            Ab[0][sI][n] = *(const bf16x8*)(wbase + (size_t)n * nstr + (size_t)sI * 512);
    }
    #pragma unroll
    for (int c = 0; c < NC2; ++c) {
        const int cur = c & 1;
        if (c + 1 < NC2) {
            const int nxt = cur ^ 1;
            #pragma unroll
            for (int sI = 0; sI < CH; ++sI) {
                int st = (c + 1) * CH + sI;
                Bb[nxt][sI] = *(const bf16x8*)(bbase + (size_t)st * 512);
                #pragma unroll
                for (int n = 0; n < 4; ++n)
                    Ab[nxt][sI][n] = *(const bf16x8*)(wbase + (size_t)n * nstr + (size_t)st * 512);
            }
        }
        #pragma unroll
        for (int sI = 0; sI < CH; ++sI) {
            acc0 = __builtin_amdgcn_mfma_f32_32x32x16_bf16(Ab[cur][sI][0], Bb[cur][sI], acc0, 0, 0, 0);
            acc1 = __builtin_amdgcn_mfma_f32_32x32x16_bf16(Ab[cur][sI][1], Bb[cur][sI], acc1, 0, 0, 0);
            acc2 = __builtin_amdgcn_mfma_f32_32x32x16_bf16(Ab[cur][sI][2], Bb[cur][sI], acc2, 0, 0, 0);
            acc3 = __builtin_amdgcn_mfma_f32_32x32x16_bf16(Ab[cur][sI][3], Bb[cur][sI], acc3, 0, 0, 0);
        }
    }

    // coef combine (per-wave partial), dump plane w to LDS
    const int b = bt * 32 + m;
    float4 cf = *(const float4*)(coef + b * 4);
    #pragma unroll
    for (int g = 0; g < 4; ++g)
        #pragma unroll
        for (int j = 0; j < 4; ++j) {
            int rI = g * 4 + j;
            float v = cf.x * acc0[rI] + cf.y * acc1[rI] + cf.z * acc2[rI] + cf.w * acc3[rI];
            red[w * 1024 + (8 * g + 4 * h + j) * 32 + m] = v;
        }
    __syncthreads();
    // wave w reduces + stores rows of group g=w
    {
        float vv[4];
        #pragma unroll
        for (int j = 0; j < 4; ++j) {
            int row = 8 * w + 4 * h + j;
            float v = red[row * 32 + m] + red[1024 + row * 32 + m]
                    + red[2048 + row * 32 + m] + red[3072 + row * 32 + m];
            if (ELU) v = (v > 0.f) ? v : expm1f(v);
            vv[j] = v;
        }
        if (OUT_BF16) {
            // o = ot*32 + 8w + 4h + j -> next layer's B-frag pos (NKS_next = 36)
            size_t off = (((size_t)bt * 36 + ot * 2 + (w >> 1)) * 64
                          + (w & 1) * 32 + m) * 8 + 4 * h;
            ushort4 pk;
            pk.x = f2bf(vv[0]); pk.y = f2bf(vv[1]); pk.z = f2bf(vv[2]); pk.w = f2bf(vv[3]);
            *(ushort4*)(HoutF + off) = pk;
        } else {
            int orow = ot * 32 + 8 * w + 4 * h;
            #pragma unroll
            for (int j = 0; j < 4; ++j)
                if (orow + j < Oreal) outF[(size_t)b * Oreal + orow + j] = vv[j];
        }
    }
}

__global__ void __launch_bounds__(256, 2) layer0_kernel(
    const unsigned short* __restrict__ Wf0, const unsigned short* __restrict__ xf,
    const float* __restrict__ coef, unsigned short* __restrict__ H1f)
{
    __shared__ float red[4 * 1024];
    layer_phase<true, true, 384, 512>(Wf0, xf, coef, H1f, nullptr, 512,
                                      red, blockIdx.x, threadIdx.x);
}
__global__ void __launch_bounds__(256, 2) layer1_kernel(
    const unsigned short* __restrict__ Wf1, const unsigned short* __restrict__ H1f,
    const float* __restrict__ coef, unsigned short* __restrict__ H2f)
{
    __shared__ float red[4 * 1024];
    layer_phase<true, true, 576, 512>(Wf1, H1f, coef, H2f, nullptr, 512,
                                      red, blockIdx.x, threadIdx.x);
}
__global__ void __launch_bounds__(256, 2) layer2_kernel(
    const unsigned short* __restrict__ Wf2, const unsigned short* __restrict__ H2f,
    const float* __restrict__ coef, float* __restrict__ outF)
{
    __shared__ float red[4 * 1024];
    layer_phase<false, false, 576, 320>(Wf2, H2f, coef, nullptr, outF, 311,
                                        red, blockIdx.x, threadIdx.x);
}

extern "C" void kernel_launch(void* const* d_in, const int* in_sizes, int n_in,
                              void* d_out, int out_size, void* d_ws, size_t ws_size,
                              hipStream_t stream) {
    (void)in_sizes; (void)n_in; (void)out_size; (void)ws_size;
    const float* x  = (const float*)d_in[0];
    const float* W0 = (const float*)d_in[1];
    const float* W1 = (const float*)d_in[2];
    const float* W2 = (const float*)d_in[3];
    const float* b0 = (const float*)d_in[4];
    const float* b1 = (const float*)d_in[5];
    const float* b2 = (const float*)d_in[6];
    float* out = (float*)d_out;

    char* wsb = (char*)d_ws;
    float*          coef = (float*)(wsb + 0);                  //   16384 B
    unsigned short* xf   = (unsigned short*)(wsb + 16384);     // (32,24,64,8)
    unsigned short* H1f  = (unsigned short*)(wsb + 802816);    // (32,36,64,8)
    unsigned short* H2f  = (unsigned short*)(wsb + 1982464);   // (32,36,64,8)
    unsigned short* Wf0  = (unsigned short*)(wsb + 3162112);   // (4,16,24,64,8)
    unsigned short* Wf1  = (unsigned short*)(wsb + 4734976);   // (4,16,36,64,8)
    unsigned short* Wf2  = (unsigned short*)(wsb + 7094272);   // (4,10,36,64,8)

    phaseA_kernel<<<dim3(200), dim3(256), 0, stream>>>(
        x, W0, W1, W2, b0, b1, b2, coef, xf, H1f, H2f, Wf0, Wf1, Wf2);
    layer0_kernel<<<dim3(512), dim3(256), 0, stream>>>(Wf0, xf,  coef, H1f);
    layer1_kernel<<<dim3(512), dim3(256), 0, stream>>>(Wf1, H1f, coef, H2f);
    layer2_kernel<<<dim3(320), dim3(256), 0, stream>>>(Wf2, H2f, coef, out);
}